// Round 3
// baseline (323.314 us; speedup 1.0000x reference)
//
#include <hip/hip_runtime.h>
#include <math.h>

#define N_NODES 50000
#define DEG 16
#define IN_F 256
#define NH 4
#define OUT_F 64
#define HF (NH * OUT_F)   // 256
#define NEG_SLOPE 0.2f

#define BM 64
#define BN 64
#define BK 16

// ---- per-head GEMM: h_head[N,64] = feat[N,256] @ W[:, head*64 : head*64+64]
// Fused epilogue: arow[n] = sum_f h*attn_l[head,f], acol[n] = sum_f h*attn_r[head,f]
__global__ __launch_bounds__(256) void sgemm_attn_kernel(const float* __restrict__ A,
                                                         const float* __restrict__ B,
                                                         const float* __restrict__ attn_l,
                                                         const float* __restrict__ attn_r,
                                                         float* __restrict__ C,
                                                         float* __restrict__ arow_o,
                                                         float* __restrict__ acol_o,
                                                         int M, int head) {
    __shared__ float As[BK][BM + 4];
    __shared__ float Bs[BK][BN + 4];

    const int t  = threadIdx.x;
    const int tx = t & 15;        // 0..15 -> col group (4 cols each)
    const int ty = t >> 4;        // 0..15 -> row group (4 rows each)
    const int m0 = blockIdx.x * BM;
    const int n0 = head * BN;     // column offset into W / attn params

    float acc[4][4] = {};

    const int arow  = t >> 2;        // 0..63
    const int acol4 = (t & 3) * 4;   // 0,4,8,12
    const int brow  = t >> 4;        // 0..15
    const int bcol4 = (t & 15) * 4;  // 0..60

    for (int k0 = 0; k0 < IN_F; k0 += BK) {
        int gm = m0 + arow;
        float4 av = make_float4(0.f, 0.f, 0.f, 0.f);
        if (gm < M) av = *(const float4*)(A + (long long)gm * IN_F + k0 + acol4);
        As[acol4 + 0][arow] = av.x;
        As[acol4 + 1][arow] = av.y;
        As[acol4 + 2][arow] = av.z;
        As[acol4 + 3][arow] = av.w;
        float4 bv = *(const float4*)(B + (long long)(k0 + brow) * HF + n0 + bcol4);
        *(float4*)&Bs[brow][bcol4] = bv;
        __syncthreads();

#pragma unroll
        for (int kk = 0; kk < BK; ++kk) {
            float a[4], b[4];
#pragma unroll
            for (int i = 0; i < 4; ++i) a[i] = As[kk][ty * 4 + i];
#pragma unroll
            for (int j = 0; j < 4; ++j) b[j] = Bs[kk][tx * 4 + j];
#pragma unroll
            for (int i = 0; i < 4; ++i)
#pragma unroll
                for (int j = 0; j < 4; ++j) acc[i][j] += a[i] * b[j];
        }
        __syncthreads();
    }

    float al[4], ar[4];
#pragma unroll
    for (int j = 0; j < 4; ++j) {
        al[j] = attn_l[n0 + tx * 4 + j];
        ar[j] = attn_r[n0 + tx * 4 + j];
    }

#pragma unroll
    for (int i = 0; i < 4; ++i) {
        int gm = m0 + ty * 4 + i;
        float pl = 0.f, pr = 0.f;
#pragma unroll
        for (int j = 0; j < 4; ++j) {
            pl += acc[i][j] * al[j];
            pr += acc[i][j] * ar[j];
        }
        // reduce across the 16 tx lanes (they are contiguous within the wave)
#pragma unroll
        for (int off = 1; off < 16; off <<= 1) {
            pl += __shfl_xor(pl, off);
            pr += __shfl_xor(pr, off);
        }
        if (gm < M) {
            float4 v = make_float4(acc[i][0], acc[i][1], acc[i][2], acc[i][3]);
            *(float4*)(C + (long long)gm * OUT_F + tx * 4) = v;
            if (tx == 0) {
                arow_o[gm] = pl;
                acol_o[gm] = pr;
            }
        }
    }
}

// ---- edge softmax + weighted aggregation, one head per launch ----
// One 64-lane wave per dst. Lanes 0..15 score the 16 incoming edges,
// then every lane accumulates one output feature over the 16 gathered rows.
__global__ __launch_bounds__(256) void agg_kernel(const int* __restrict__ col_ind,
                                                  const float* __restrict__ h,
                                                  const float* __restrict__ arow,
                                                  const float* __restrict__ acol,
                                                  float* __restrict__ out, int head) {
    const int wave = threadIdx.x >> 6;
    const int lane = threadIdx.x & 63;
    const int dst  = blockIdx.x * 4 + wave;
    if (dst >= N_NODES) return;
    const int ebase = dst * DEG;

    float s = -INFINITY;
    if (lane < DEG) {
        int src = col_ind[ebase + lane];
        src = (src < 0) ? 0 : (src >= N_NODES ? N_NODES - 1 : src);  // fault guard
        float v = arow[dst] + acol[src];
        s = (v >= 0.f) ? v : NEG_SLOPE * v;
    }
    float m = s;
#pragma unroll
    for (int off = 32; off; off >>= 1) m = fmaxf(m, __shfl_xor(m, off));
    float ex = (lane < DEG) ? expf(s - m) : 0.f;
    float sum = ex;
#pragma unroll
    for (int off = 32; off; off >>= 1) sum += __shfl_xor(sum, off);
    const float inv = 1.f / sum;

    float acc = 0.f;
#pragma unroll
    for (int e = 0; e < DEG; ++e) {
        float a = __shfl(ex, e) * inv;
        int src = col_ind[ebase + e];   // wave-uniform load (broadcast)
        src = (src < 0) ? 0 : (src >= N_NODES ? N_NODES - 1 : src);
        acc += a * h[(long long)src * OUT_F + lane];
    }
    out[(long long)dst * HF + head * OUT_F + lane] = acc;
}

extern "C" void kernel_launch(void* const* d_in, const int* in_sizes, int n_in,
                              void* d_out, int out_size, void* d_ws, size_t ws_size,
                              hipStream_t stream) {
    // setup_inputs order: row_ptr, col_ind, col_ptr, row_ind (integer -> const int*),
    //                     feat(f32), W(f32), attn_l(f32), attn_r(f32)
    const int*   col_ind = (const int*)d_in[1];
    const float* feat    = (const float*)d_in[4];
    const float* W       = (const float*)d_in[5];
    const float* attn_l  = (const float*)d_in[6];
    const float* attn_r  = (const float*)d_in[7];
    float* out = (float*)d_out;

    // workspace: h_head (N*64 f32 = 12.8 MB) + arow (N) + acol (N) = 13.2 MB
    const size_t need = (size_t)N_NODES * OUT_F * 4 + 2 * (size_t)N_NODES * 4;
    if (ws_size < need) return;   // too small: clean absmax failure, not a fault

    float* h_head = (float*)d_ws;
    float* arow   = h_head + (size_t)N_NODES * OUT_F;
    float* acol   = arow + N_NODES;

    const int gemm_grid = (N_NODES + BM - 1) / BM;
    const int agg_grid  = (N_NODES + 3) / 4;

    for (int head = 0; head < NH; ++head) {
        sgemm_attn_kernel<<<gemm_grid, 256, 0, stream>>>(feat, W, attn_l, attn_r,
                                                         h_head, arow, acol,
                                                         N_NODES, head);
        agg_kernel<<<agg_grid, 256, 0, stream>>>(col_ind, h_head, arow, acol, out, head);
    }
}

// Round 4
// 198.732 us; speedup vs baseline: 1.6269x; 1.6269x over previous
//
#include <hip/hip_runtime.h>
#include <math.h>

#define N_NODES 50000
#define DEG 16
#define IN_F 256
#define NH 4
#define OUT_F 64
#define HF 256          // NH * OUT_F
#define NEG_SLOPE 0.2f

typedef float  floatx4 __attribute__((ext_vector_type(4)));
typedef short  short8  __attribute__((ext_vector_type(8)));

__device__ __forceinline__ ushort f2bf(float x) {   // RNE fp32->bf16
    unsigned u = __float_as_uint(x);
    u = (u + 0x7FFFu + ((u >> 16) & 1u)) >> 16;
    return (ushort)u;
}
__device__ __forceinline__ float bf2f(ushort b) {
    return __uint_as_float(((unsigned)b) << 16);
}

// ---- cast feat fp32[N,256] -> bf16, 8 elems/thread (exact grid: 6250*256*8) ----
__global__ __launch_bounds__(256) void cast_feat_kernel(const float* __restrict__ f,
                                                        ushort* __restrict__ o) {
    const int idx = blockIdx.x * 256 + threadIdx.x;
    const float4 a = ((const float4*)f)[idx * 2];
    const float4 b = ((const float4*)f)[idx * 2 + 1];
    ushort4 lo = make_ushort4(f2bf(a.x), f2bf(a.y), f2bf(a.z), f2bf(a.w));
    ushort4 hi = make_ushort4(f2bf(b.x), f2bf(b.y), f2bf(b.z), f2bf(b.w));
    ((ushort4*)o)[idx * 2]     = lo;
    ((ushort4*)o)[idx * 2 + 1] = hi;
}

// ---- W[256,256] fp32 -> Wt[n][k] bf16 (transposed), 16 blocks of 64x64 tiles ----
__global__ __launch_bounds__(256) void cast_wt_kernel(const float* __restrict__ W,
                                                      ushort* __restrict__ Wt) {
    __shared__ float tile[64][65];
    const int bx = blockIdx.x & 3;    // n tile
    const int by = blockIdx.x >> 2;   // k tile
#pragma unroll
    for (int i = 0; i < 16; ++i) {
        int idx = threadIdx.x + 256 * i;
        int r = idx >> 6, c = idx & 63;
        tile[r][c] = W[(by * 64 + r) * 256 + bx * 64 + c];
    }
    __syncthreads();
#pragma unroll
    for (int i = 0; i < 16; ++i) {
        int idx = threadIdx.x + 256 * i;
        int n = idx >> 6, k = idx & 63;
        Wt[(size_t)(bx * 64 + n) * 256 + by * 64 + k] = f2bf(tile[k][n]);
    }
}

// ---- MFMA GEMM: H[M,256] = feat_bf[M,256] @ W  (B given as Wt[n][k]) ----
// 128x128 block tile, 4 waves in 2x2, each wave 4x4 MFMA tiles of 16x16x32.
// Epilogue: H in bf16 + fused attn dots (wave's 64-col region == one head).
__global__ __launch_bounds__(256) void mfma_gemm_kernel(const ushort* __restrict__ A,
                                                        const ushort* __restrict__ Bt,
                                                        const float* __restrict__ attn_l,
                                                        const float* __restrict__ attn_r,
                                                        ushort* __restrict__ H,
                                                        float* __restrict__ arow_g,
                                                        float* __restrict__ acol_g,
                                                        int M) {
    // chunk layout: slot = kc*128 + row, each slot = 8 bf16 (16 B)
    __shared__ __align__(16) ushort Abuf[4096];
    __shared__ __align__(16) ushort Bbuf[4096];

    const int tid  = threadIdx.x;
    const int w    = tid >> 6;
    const int lane = tid & 63;
    const int wm   = w >> 1, wn = w & 1;
    const int g    = lane >> 4;     // kc group / row-quad group
    const int r    = lane & 15;

    const int m0 = blockIdx.x * 128;
    const int nb = blockIdx.y;      // 0..1 (heads nb*2, nb*2+1)
    const int n0 = nb * 128;

    // staging: thread handles chunks (row0, kc) and (row0+64, kc)
    const int row0 = tid >> 2;      // 0..63
    const int kc   = tid & 3;
    const int gmA0 = min(m0 + row0, M - 1);
    const int gmA1 = min(m0 + row0 + 64, M - 1);

    floatx4 acc[4][4];
#pragma unroll
    for (int i = 0; i < 4; ++i)
#pragma unroll
        for (int j = 0; j < 4; ++j) acc[i][j] = (floatx4)(0.f);

    for (int k0 = 0; k0 < IN_F; k0 += 32) {
        short8 va0 = *(const short8*)(A + (size_t)gmA0 * 256 + k0 + kc * 8);
        short8 va1 = *(const short8*)(A + (size_t)gmA1 * 256 + k0 + kc * 8);
        short8 vb0 = *(const short8*)(Bt + (size_t)(n0 + row0) * 256 + k0 + kc * 8);
        short8 vb1 = *(const short8*)(Bt + (size_t)(n0 + row0 + 64) * 256 + k0 + kc * 8);
        __syncthreads();   // previous compute done reading LDS
        *(short8*)&Abuf[(kc * 128 + row0) * 8]        = va0;
        *(short8*)&Abuf[(kc * 128 + row0 + 64) * 8]   = va1;
        *(short8*)&Bbuf[(kc * 128 + row0) * 8]        = vb0;
        *(short8*)&Bbuf[(kc * 128 + row0 + 64) * 8]   = vb1;
        __syncthreads();   // tiles visible

        short8 af[4], bf[4];
#pragma unroll
        for (int i = 0; i < 4; ++i)
            af[i] = *(const short8*)&Abuf[(g * 128 + wm * 64 + i * 16 + r) * 8];
#pragma unroll
        for (int j = 0; j < 4; ++j)
            bf[j] = *(const short8*)&Bbuf[(g * 128 + wn * 64 + j * 16 + r) * 8];
#pragma unroll
        for (int i = 0; i < 4; ++i)
#pragma unroll
            for (int j = 0; j < 4; ++j)
                acc[i][j] = __builtin_amdgcn_mfma_f32_16x16x32_bf16(af[i], bf[j], acc[i][j], 0, 0, 0);
    }

    // ---- epilogue: C/D layout col = lane&15 (=r), row = g*4 + reg ----
    const int head = nb * 2 + wn;
    float al[4], ar[4];
#pragma unroll
    for (int j = 0; j < 4; ++j) {
        al[j] = attn_l[head * 64 + j * 16 + r];
        ar[j] = attn_r[head * 64 + j * 16 + r];
    }

#pragma unroll
    for (int i = 0; i < 4; ++i) {
#pragma unroll
        for (int reg = 0; reg < 4; ++reg) {
            const int gm = m0 + wm * 64 + i * 16 + g * 4 + reg;
            float pl = 0.f, pr = 0.f;
#pragma unroll
            for (int j = 0; j < 4; ++j) {
                float v = acc[i][j][reg];
                pl += v * al[j];
                pr += v * ar[j];
            }
            if (gm < M) {
#pragma unroll
                for (int j = 0; j < 4; ++j)
                    H[(size_t)gm * 256 + n0 + wn * 64 + j * 16 + r] = f2bf(acc[i][j][reg]);
            }
            // reduce over the 16 contiguous r-lanes
#pragma unroll
            for (int off = 1; off < 16; off <<= 1) {
                pl += __shfl_xor(pl, off);
                pr += __shfl_xor(pr, off);
            }
            if (r == 0 && gm < M) {
                arow_g[gm * NH + head] = pl;
                acol_g[gm * NH + head] = pr;
            }
        }
    }
}

// ---- fused softmax+aggregate, all heads: one wave per dst ----
// lane = hidx*16 + e for scoring; lane handles out feats [lane*4, lane*4+3]
// (head = lane>>4 for both roles — alpha broadcast stays within the wave).
__global__ __launch_bounds__(256) void agg_kernel(const int* __restrict__ col_ind,
                                                  const ushort* __restrict__ H,
                                                  const float* __restrict__ arow_g,
                                                  const float* __restrict__ acol_g,
                                                  float* __restrict__ out) {
    const int wave = threadIdx.x >> 6, lane = threadIdx.x & 63;
    const int dst  = blockIdx.x * 4 + wave;
    const int hidx = lane >> 4, e = lane & 15;

    int src = col_ind[dst * DEG + e];
    src = src < 0 ? 0 : (src >= N_NODES ? N_NODES - 1 : src);   // fault guard
    float s = arow_g[dst * NH + hidx] + acol_g[src * NH + hidx];
    s = (s >= 0.f) ? s : NEG_SLOPE * s;
    float m = s;
#pragma unroll
    for (int off = 1; off < 16; off <<= 1) m = fmaxf(m, __shfl_xor(m, off));
    float ex = expf(s - m);
    float sum = ex;
#pragma unroll
    for (int off = 1; off < 16; off <<= 1) sum += __shfl_xor(sum, off);
    const float alpha = ex / sum;     // lane (hidx, e)

    float4 acc = make_float4(0.f, 0.f, 0.f, 0.f);
#pragma unroll
    for (int ee = 0; ee < DEG; ++ee) {
        int   s_e = __shfl(src, ee);                     // lanes 0..15 hold e=0..15
        float a   = __shfl(alpha, (lane & 48) + ee);     // alpha[my head][ee]
        ushort4 hv = *(const ushort4*)(H + (size_t)s_e * 256 + lane * 4);
        acc.x += a * bf2f(hv.x);
        acc.y += a * bf2f(hv.y);
        acc.z += a * bf2f(hv.z);
        acc.w += a * bf2f(hv.w);
    }
    *(float4*)(out + (size_t)dst * 256 + lane * 4) = acc;
}

extern "C" void kernel_launch(void* const* d_in, const int* in_sizes, int n_in,
                              void* d_out, int out_size, void* d_ws, size_t ws_size,
                              hipStream_t stream) {
    const int*   col_ind = (const int*)d_in[1];
    const float* feat    = (const float*)d_in[4];
    const float* W       = (const float*)d_in[5];
    const float* attn_l  = (const float*)d_in[6];
    const float* attn_r  = (const float*)d_in[7];
    float* out = (float*)d_out;

    // ws layout (all 16B aligned): feat_bf 25.6MB | Wt 128KB | h_bf 25.6MB | arow | acol
    ushort* feat_bf = (ushort*)d_ws;
    ushort* Wt      = feat_bf + (size_t)N_NODES * IN_F;
    ushort* h_bf    = Wt + 256 * 256;
    float*  arow    = (float*)(h_bf + (size_t)N_NODES * HF);
    float*  acol    = arow + (size_t)N_NODES * NH;

    const size_t need = ((size_t)N_NODES * IN_F + 256 * 256 + (size_t)N_NODES * HF) * 2
                      + (size_t)N_NODES * NH * 4 * 2;
    if (ws_size < need) return;

    cast_feat_kernel<<<(N_NODES * IN_F) / (256 * 8), 256, 0, stream>>>(feat, feat_bf);
    cast_wt_kernel<<<16, 256, 0, stream>>>(W, Wt);

    dim3 gg((N_NODES + 127) / 128, 2);
    mfma_gemm_kernel<<<gg, 256, 0, stream>>>(feat_bf, Wt, attn_l, attn_r,
                                             h_bf, arow, acol, N_NODES);

    agg_kernel<<<N_NODES / 4, 256, 0, stream>>>(col_ind, h_bf, arow, acol, out);
}

// Round 5
// 193.579 us; speedup vs baseline: 1.6702x; 1.0266x over previous
//
#include <hip/hip_runtime.h>
#include <math.h>

#define N_NODES 50000
#define DEG 16
#define IN_F 256
#define NH 4
#define OUT_F 64
#define HF 256          // NH * OUT_F
#define NEG_SLOPE 0.2f

typedef float  floatx4 __attribute__((ext_vector_type(4)));
typedef short  short8  __attribute__((ext_vector_type(8)));

__device__ __forceinline__ ushort f2bf(float x) {   // RNE fp32->bf16
    unsigned u = __float_as_uint(x);
    u = (u + 0x7FFFu + ((u >> 16) & 1u)) >> 16;
    return (ushort)u;
}
__device__ __forceinline__ float bf2f(ushort b) {
    return __uint_as_float(((unsigned)b) << 16);
}
__device__ __forceinline__ void gld16(const void* g, void* l) {
    __builtin_amdgcn_global_load_lds((const __attribute__((address_space(1))) void*)g,
                                     (__attribute__((address_space(3))) void*)l, 16, 0, 0);
}

// ---- cast feat fp32[N,256] -> bf16, 8 elems/thread ----
__global__ __launch_bounds__(256) void cast_feat_kernel(const float* __restrict__ f,
                                                        ushort* __restrict__ o) {
    const int idx = blockIdx.x * 256 + threadIdx.x;
    const float4 a = ((const float4*)f)[idx * 2];
    const float4 b = ((const float4*)f)[idx * 2 + 1];
    ushort4 lo = make_ushort4(f2bf(a.x), f2bf(a.y), f2bf(a.z), f2bf(a.w));
    ushort4 hi = make_ushort4(f2bf(b.x), f2bf(b.y), f2bf(b.z), f2bf(b.w));
    ((ushort4*)o)[idx * 2]     = lo;
    ((ushort4*)o)[idx * 2 + 1] = hi;
}

// ---- W[256,256] fp32 -> Wt[n][k] bf16 (transposed) ----
__global__ __launch_bounds__(256) void cast_wt_kernel(const float* __restrict__ W,
                                                      ushort* __restrict__ Wt) {
    __shared__ float tile[64][65];
    const int bx = blockIdx.x & 3;    // n tile
    const int by = blockIdx.x >> 2;   // k tile
#pragma unroll
    for (int i = 0; i < 16; ++i) {
        int idx = threadIdx.x + 256 * i;
        int r = idx >> 6, c = idx & 63;
        tile[r][c] = W[(by * 64 + r) * 256 + bx * 64 + c];
    }
    __syncthreads();
#pragma unroll
    for (int i = 0; i < 16; ++i) {
        int idx = threadIdx.x + 256 * i;
        int n = idx >> 6, k = idx & 63;
        Wt[(size_t)(bx * 64 + n) * 256 + by * 64 + k] = f2bf(tile[k][n]);
    }
}

// ---- MFMA GEMM: H[M,256] = feat_bf @ W (B as Wt[n][k]), global_load_lds staging.
// 128x128 tile, 4 waves 2x2, 4x4 frags of 16x16x32. LDS tile layout:
// ushort idx = row*32 + kc*8  (row-major, lane-order contiguous for glld).
__global__ __launch_bounds__(256) void mfma_gemm_kernel(const ushort* __restrict__ A,
                                                        const ushort* __restrict__ Bt,
                                                        const float* __restrict__ attn_l,
                                                        const float* __restrict__ attn_r,
                                                        ushort* __restrict__ H,
                                                        float* __restrict__ arow_g,
                                                        float* __restrict__ acol_g,
                                                        int M) {
    __shared__ __align__(16) ushort smem[8192];   // A tile [0,4096), B tile [4096,8192)
    ushort* Abuf = smem;
    ushort* Bbuf = smem + 4096;

    const int tid  = threadIdx.x;
    const int w    = tid >> 6;
    const int lane = tid & 63;
    const int wm   = w >> 1, wn = w & 1;
    const int g    = lane >> 4;     // kc group
    const int r    = lane & 15;

    const int m0 = blockIdx.x * 128;
    const int nb = blockIdx.y;      // 0..1
    const int n0 = nb * 128;

    // staging: wave w covers rows [w*32, w*32+32) of both tiles, 2 segments of 16 rows
    const int srow = w * 32 + (lane >> 2);
    const int kc8  = (lane & 3) * 8;
    const size_t gA0 = (size_t)min(m0 + srow,      M - 1) * 256 + kc8;
    const size_t gA1 = (size_t)min(m0 + srow + 16, M - 1) * 256 + kc8;
    const size_t gB0 = (size_t)(n0 + srow)      * 256 + kc8;
    const size_t gB1 = (size_t)(n0 + srow + 16) * 256 + kc8;
    ushort* lA0 = Abuf + (size_t)(w * 32)      * 32 + lane * 8;
    ushort* lA1 = Abuf + (size_t)(w * 32 + 16) * 32 + lane * 8;
    ushort* lB0 = Bbuf + (size_t)(w * 32)      * 32 + lane * 8;
    ushort* lB1 = Bbuf + (size_t)(w * 32 + 16) * 32 + lane * 8;

    floatx4 acc[4][4];
#pragma unroll
    for (int i = 0; i < 4; ++i)
#pragma unroll
        for (int j = 0; j < 4; ++j) acc[i][j] = (floatx4)(0.f);

    for (int k0 = 0; k0 < IN_F; k0 += 32) {
        __syncthreads();                       // previous compute done reading LDS
        gld16(A + gA0 + k0, lA0);
        gld16(A + gA1 + k0, lA1);
        gld16(Bt + gB0 + k0, lB0);
        gld16(Bt + gB1 + k0, lB1);
        __syncthreads();                       // drains vmcnt: tiles visible

        short8 af[4], bfr[4];
#pragma unroll
        for (int i = 0; i < 4; ++i)
            af[i] = *(const short8*)&Abuf[(size_t)(wm * 64 + i * 16 + r) * 32 + g * 8];
#pragma unroll
        for (int j = 0; j < 4; ++j)
            bfr[j] = *(const short8*)&Bbuf[(size_t)(wn * 64 + j * 16 + r) * 32 + g * 8];
#pragma unroll
        for (int i = 0; i < 4; ++i)
#pragma unroll
            for (int j = 0; j < 4; ++j)
                acc[i][j] = __builtin_amdgcn_mfma_f32_16x16x32_bf16(af[i], bfr[j], acc[i][j], 0, 0, 0);
    }

    // ---- epilogue via per-wave LDS transpose (4 KB/wave inside smem) ----
    // C/D layout: col = r, row = g*4 + reg  (within each 16x16 tile)
    const int head = nb * 2 + wn;
    const int rr = lane >> 2;          // transposed read: row within i-tile
    const int cb = (lane & 3) * 16;    // 16-col chunk base
    float al[16], ar[16];
#pragma unroll
    for (int q = 0; q < 4; ++q) {
        *(float4*)&al[q * 4] = *(const float4*)(attn_l + head * 64 + cb + q * 4);
        *(float4*)&ar[q * 4] = *(const float4*)(attn_r + head * 64 + cb + q * 4);
    }
    float* wreg = (float*)smem + w * 1024;   // 16 rows x 64 cols fp32

#pragma unroll
    for (int i = 0; i < 4; ++i) {
        __syncthreads();   // LDS free (K-loop frag reads / previous i's reads done)
#pragma unroll
        for (int j = 0; j < 4; ++j)
#pragma unroll
            for (int reg = 0; reg < 4; ++reg)
                wreg[(g * 4 + reg) * 64 + j * 16 + r] = acc[i][j][reg];
        __syncthreads();

        float v[16];
#pragma unroll
        for (int q = 0; q < 4; ++q)
            *(float4*)&v[q * 4] = *(const float4*)&wreg[rr * 64 + cb + q * 4];

        float pl = 0.f, pr = 0.f;
#pragma unroll
        for (int k = 0; k < 16; ++k) { pl += v[k] * al[k]; pr += v[k] * ar[k]; }
        pl += __shfl_xor(pl, 1); pl += __shfl_xor(pl, 2);
        pr += __shfl_xor(pr, 1); pr += __shfl_xor(pr, 2);

        const int gm = m0 + wm * 64 + i * 16 + rr;
        if (gm < M) {
            short8 h0, h1;
#pragma unroll
            for (int k = 0; k < 8; ++k) { h0[k] = (short)f2bf(v[k]); h1[k] = (short)f2bf(v[8 + k]); }
            ushort* dst = H + (size_t)gm * 256 + n0 + wn * 64 + cb;
            *(short8*)dst       = h0;
            *(short8*)(dst + 8) = h1;
            if ((lane & 3) == 0) {
                arow_g[gm * NH + head] = pl;
                acol_g[gm * NH + head] = pr;
            }
        }
    }
}

// ---- fused softmax+aggregate: one wave per dst, 2 edges per gather inst ----
// Scoring: lane = hidx*16 + e. Accumulation: lane covers feats (lane&31)*8..+7
// of edge 2t+(lane>>5); halves combined via shfl_xor 32.
__global__ __launch_bounds__(256) void agg_kernel(const int* __restrict__ col_ind,
                                                  const ushort* __restrict__ H,
                                                  const float* __restrict__ arow_g,
                                                  const float* __restrict__ acol_g,
                                                  float* __restrict__ out) {
    const int wave = threadIdx.x >> 6, lane = threadIdx.x & 63;
    const int dst  = blockIdx.x * 4 + wave;
    const int hidx = lane >> 4, e_s = lane & 15;

    int src = col_ind[dst * DEG + e_s];
    src = src < 0 ? 0 : (src >= N_NODES ? N_NODES - 1 : src);   // fault guard
    float s = arow_g[dst * NH + hidx] + acol_g[src * NH + hidx];
    s = (s >= 0.f) ? s : NEG_SLOPE * s;
    float m = s;
#pragma unroll
    for (int off = 1; off < 16; off <<= 1) m = fmaxf(m, __shfl_xor(m, off));
    float ex = expf(s - m);
    float sum = ex;
#pragma unroll
    for (int off = 1; off < 16; off <<= 1) sum += __shfl_xor(sum, off);
    const float alpha = ex / sum;     // lane (hidx, e)

    const int fb     = (lane & 31) * 8;   // feature base (32 B fp32 / 16 B bf16)
    const int head_a = fb >> 6;           // head owning these 8 feats
    const int half   = lane >> 5;

    float acc[8];
#pragma unroll
    for (int k = 0; k < 8; ++k) acc[k] = 0.f;

#pragma unroll
    for (int t = 0; t < DEG / 2; ++t) {
        const int e = 2 * t + half;
        const int row = __shfl(src, e);                    // lanes 0..15 hold e=0..15
        const float a = __shfl(alpha, head_a * 16 + e);
        short8 hv = *(const short8*)(H + (size_t)row * 256 + fb);
#pragma unroll
        for (int k = 0; k < 8; ++k) acc[k] += a * bf2f((ushort)hv[k]);
    }
#pragma unroll
    for (int k = 0; k < 8; ++k) acc[k] += __shfl_xor(acc[k], 32);

    // full-wave coalesced store: lane writes 4 floats of its half
    const int qb = half * 4;
    float4 o4 = make_float4(acc[qb], acc[qb + 1], acc[qb + 2], acc[qb + 3]);
    *(float4*)(out + (size_t)dst * 256 + fb + qb) = o4;
}

extern "C" void kernel_launch(void* const* d_in, const int* in_sizes, int n_in,
                              void* d_out, int out_size, void* d_ws, size_t ws_size,
                              hipStream_t stream) {
    const int*   col_ind = (const int*)d_in[1];
    const float* feat    = (const float*)d_in[4];
    const float* W       = (const float*)d_in[5];
    const float* attn_l  = (const float*)d_in[6];
    const float* attn_r  = (const float*)d_in[7];
    float* out = (float*)d_out;

    // ws: feat_bf 25.6MB | Wt 128KB | h_bf 25.6MB | arow 0.8MB | acol 0.8MB
    ushort* feat_bf = (ushort*)d_ws;
    ushort* Wt      = feat_bf + (size_t)N_NODES * IN_F;
    ushort* h_bf    = Wt + 256 * 256;
    float*  arow    = (float*)(h_bf + (size_t)N_NODES * HF);
    float*  acol    = arow + (size_t)N_NODES * NH;

    const size_t need = ((size_t)N_NODES * IN_F + 256 * 256 + (size_t)N_NODES * HF) * 2
                      + (size_t)N_NODES * NH * 4 * 2;
    if (ws_size < need) return;

    cast_feat_kernel<<<(N_NODES * IN_F) / (256 * 8), 256, 0, stream>>>(feat, feat_bf);
    cast_wt_kernel<<<16, 256, 0, stream>>>(W, Wt);

    dim3 gg((N_NODES + 127) / 128, 2);
    mfma_gemm_kernel<<<gg, 256, 0, stream>>>(feat_bf, Wt, attn_l, attn_r,
                                             h_bf, arow, acol, N_NODES);

    agg_kernel<<<N_NODES / 4, 256, 0, stream>>>(col_ind, h_bf, arow, acol, out);
}

// Round 6
// 191.974 us; speedup vs baseline: 1.6842x; 1.0084x over previous
//
#include <hip/hip_runtime.h>
#include <math.h>

#define N_NODES 50000
#define DEG 16
#define IN_F 256
#define NH 4
#define OUT_F 64
#define HF 256          // NH * OUT_F
#define NEG_SLOPE 0.2f

typedef float  floatx4 __attribute__((ext_vector_type(4)));
typedef short  short8  __attribute__((ext_vector_type(8)));

__device__ __forceinline__ ushort f2bf(float x) {   // RNE fp32->bf16
    unsigned u = __float_as_uint(x);
    u = (u + 0x7FFFu + ((u >> 16) & 1u)) >> 16;
    return (ushort)u;
}
__device__ __forceinline__ float bf2f(ushort b) {
    return __uint_as_float(((unsigned)b) << 16);
}
__device__ __forceinline__ void gld16(const void* g, void* l) {
    __builtin_amdgcn_global_load_lds((const __attribute__((address_space(1))) void*)g,
                                     (__attribute__((address_space(3))) void*)l, 16, 0, 0);
}

// ---- W[256,256] fp32 -> Wt[n][k] bf16 (transposed) ----
__global__ __launch_bounds__(256) void cast_wt_kernel(const float* __restrict__ W,
                                                      ushort* __restrict__ Wt) {
    __shared__ float tile[64][65];
    const int bx = blockIdx.x & 3;    // n tile
    const int by = blockIdx.x >> 2;   // k tile
#pragma unroll
    for (int i = 0; i < 16; ++i) {
        int idx = threadIdx.x + 256 * i;
        int r = idx >> 6, c = idx & 63;
        tile[r][c] = W[(by * 64 + r) * 256 + bx * 64 + c];
    }
    __syncthreads();
#pragma unroll
    for (int i = 0; i < 16; ++i) {
        int idx = threadIdx.x + 256 * i;
        int n = idx >> 6, k = idx & 63;
        Wt[(size_t)(bx * 64 + n) * 256 + by * 64 + k] = f2bf(tile[k][n]);
    }
}

// ---- MFMA GEMM with fused fp32->bf16 A-cast + fused attn-dot epilogue ----
// H[M,256] = bf16(A_f32) @ W   (B given as Wt[n][k] bf16)
// 64x128 block tile, 4 waves 2x2 (wave tile 32x64), 2x4 frags of 16x16x32.
// A: fp32 global -> register prefetch -> cvt -> ds_write.  B: global_load_lds.
__global__ __launch_bounds__(256) void mfma_gemm_kernel(const float* __restrict__ A,
                                                        const ushort* __restrict__ Bt,
                                                        const float* __restrict__ attn_l,
                                                        const float* __restrict__ attn_r,
                                                        ushort* __restrict__ H,
                                                        float* __restrict__ arow_g,
                                                        float* __restrict__ acol_g,
                                                        int M) {
    __shared__ __align__(16) ushort smem[8192];   // A [0,2048) B [2048,6144); epi: 16KB fp32
    ushort* Abuf = smem;            // 64 rows x 32 k
    ushort* Bbuf = smem + 2048;     // 128 rows x 32 k

    const int tid  = threadIdx.x;
    const int w    = tid >> 6;
    const int lane = tid & 63;
    const int wm   = w >> 1, wn = w & 1;
    const int g    = lane >> 4;     // k-chunk group (8 bf16 each)
    const int r    = lane & 15;

    const int m0 = blockIdx.x * 64;
    const int nb = blockIdx.y;      // 0..1
    const int n0 = nb * 128;

    // staging assignment: thread t -> A row t>>2 (0..63), k-chunk t&3
    const int srow = tid >> 2;
    const int kc8  = (tid & 3) * 8;
    const int gmA  = min(m0 + srow, M - 1);
    const float*  Aptr = A + (size_t)gmA * 256 + kc8;
    const size_t  gB0  = (size_t)(n0 + srow)      * 256 + kc8;   // B rows srow, srow+64
    const size_t  gB1  = (size_t)(n0 + srow + 64) * 256 + kc8;
    ushort* lA  = Abuf + (size_t)srow * 32 + kc8;                // byte off = 16*t
    ushort* lB0 = Bbuf + (size_t)srow * 32 + kc8;
    ushort* lB1 = Bbuf + (size_t)(srow + 64) * 32 + kc8;

    floatx4 acc[2][4];
#pragma unroll
    for (int i = 0; i < 2; ++i)
#pragma unroll
        for (int j = 0; j < 4; ++j) acc[i][j] = (floatx4)(0.f);

    float4 p0 = *(const float4*)(Aptr);
    float4 p1 = *(const float4*)(Aptr + 4);

    for (int k0 = 0; k0 < IN_F; k0 += 32) {
        __syncthreads();                       // LDS consumable (prev frags read)
        short8 a8;
        a8[0] = (short)f2bf(p0.x); a8[1] = (short)f2bf(p0.y);
        a8[2] = (short)f2bf(p0.z); a8[3] = (short)f2bf(p0.w);
        a8[4] = (short)f2bf(p1.x); a8[5] = (short)f2bf(p1.y);
        a8[6] = (short)f2bf(p1.z); a8[7] = (short)f2bf(p1.w);
        *(short8*)lA = a8;
        gld16(Bt + gB0 + k0, lB0);
        gld16(Bt + gB1 + k0, lB1);
        __syncthreads();                       // drains lgkm+vm: tiles visible

        if (k0 + 32 < IN_F) {                  // prefetch next A chunk (overlaps MFMA)
            p0 = *(const float4*)(Aptr + k0 + 32);
            p1 = *(const float4*)(Aptr + k0 + 36);
        }

        short8 af[2], bfr[4];
#pragma unroll
        for (int i = 0; i < 2; ++i)
            af[i] = *(const short8*)&Abuf[(size_t)(wm * 32 + i * 16 + r) * 32 + g * 8];
#pragma unroll
        for (int j = 0; j < 4; ++j)
            bfr[j] = *(const short8*)&Bbuf[(size_t)(wn * 64 + j * 16 + r) * 32 + g * 8];
#pragma unroll
        for (int i = 0; i < 2; ++i)
#pragma unroll
            for (int j = 0; j < 4; ++j)
                acc[i][j] = __builtin_amdgcn_mfma_f32_16x16x32_bf16(af[i], bfr[j], acc[i][j], 0, 0, 0);
    }

    // ---- epilogue: per-wave LDS transpose; C/D layout col=r, row=g*4+reg ----
    const int head = nb * 2 + wn;
    const int rr = lane >> 2;          // transposed row within i-tile
    const int cb = (lane & 3) * 16;    // 16-col chunk base
    float al[16], ar[16];
#pragma unroll
    for (int q = 0; q < 4; ++q) {
        *(float4*)&al[q * 4] = *(const float4*)(attn_l + head * 64 + cb + q * 4);
        *(float4*)&ar[q * 4] = *(const float4*)(attn_r + head * 64 + cb + q * 4);
    }
    float* wreg = (float*)smem + w * 1024;   // 16 rows x 64 cols fp32 per wave

#pragma unroll
    for (int i = 0; i < 2; ++i) {
        __syncthreads();
#pragma unroll
        for (int j = 0; j < 4; ++j)
#pragma unroll
            for (int reg = 0; reg < 4; ++reg)
                wreg[(g * 4 + reg) * 64 + j * 16 + r] = acc[i][j][reg];
        __syncthreads();

        float v[16];
#pragma unroll
        for (int q = 0; q < 4; ++q)
            *(float4*)&v[q * 4] = *(const float4*)&wreg[rr * 64 + cb + q * 4];

        float pl = 0.f, pr = 0.f;
#pragma unroll
        for (int k = 0; k < 16; ++k) { pl += v[k] * al[k]; pr += v[k] * ar[k]; }
        pl += __shfl_xor(pl, 1); pl += __shfl_xor(pl, 2);
        pr += __shfl_xor(pr, 1); pr += __shfl_xor(pr, 2);

        const int gm = m0 + wm * 32 + i * 16 + rr;
        if (gm < M) {
            short8 h0, h1;
#pragma unroll
            for (int k = 0; k < 8; ++k) { h0[k] = (short)f2bf(v[k]); h1[k] = (short)f2bf(v[8 + k]); }
            ushort* dst = H + (size_t)gm * 256 + n0 + wn * 64 + cb;
            *(short8*)dst       = h0;
            *(short8*)(dst + 8) = h1;
            if ((lane & 3) == 0) {
                arow_g[gm * NH + head] = pl;
                acol_g[gm * NH + head] = pr;
            }
        }
    }
}

// ---- fused softmax+aggregate: 2 dsts per wave (16 gathers in flight) ----
// Scoring (per dst): lane = hidx*16 + e.  Gather: lane covers feats
// (lane&31)*8..+7 of edge 2t+(lane>>5); halves combined via shfl_xor 32.
__global__ __launch_bounds__(256) void agg_kernel(const int* __restrict__ col_ind,
                                                  const ushort* __restrict__ H,
                                                  const float* __restrict__ arow_g,
                                                  const float* __restrict__ acol_g,
                                                  float* __restrict__ out) {
    const int wave = threadIdx.x >> 6, lane = threadIdx.x & 63;
    const int d0   = blockIdx.x * 8 + wave * 2;
    const int d1   = d0 + 1;
    const int hidx = lane >> 4, e_s = lane & 15;

    int src0 = col_ind[d0 * DEG + e_s];
    int src1 = col_ind[d1 * DEG + e_s];
    src0 = src0 < 0 ? 0 : (src0 >= N_NODES ? N_NODES - 1 : src0);
    src1 = src1 < 0 ? 0 : (src1 >= N_NODES ? N_NODES - 1 : src1);

    float s0 = arow_g[d0 * NH + hidx] + acol_g[src0 * NH + hidx];
    float s1 = arow_g[d1 * NH + hidx] + acol_g[src1 * NH + hidx];
    s0 = (s0 >= 0.f) ? s0 : NEG_SLOPE * s0;
    s1 = (s1 >= 0.f) ? s1 : NEG_SLOPE * s1;
    float m0 = s0, m1 = s1;
#pragma unroll
    for (int off = 1; off < 16; off <<= 1) {
        m0 = fmaxf(m0, __shfl_xor(m0, off));
        m1 = fmaxf(m1, __shfl_xor(m1, off));
    }
    float ex0 = expf(s0 - m0), ex1 = expf(s1 - m1);
    float su0 = ex0, su1 = ex1;
#pragma unroll
    for (int off = 1; off < 16; off <<= 1) {
        su0 += __shfl_xor(su0, off);
        su1 += __shfl_xor(su1, off);
    }
    const float alpha0 = ex0 / su0, alpha1 = ex1 / su1;

    const int fb     = (lane & 31) * 8;
    const int head_a = fb >> 6;
    const int half   = lane >> 5;

    float acc0[8], acc1[8];
#pragma unroll
    for (int k = 0; k < 8; ++k) { acc0[k] = 0.f; acc1[k] = 0.f; }

#pragma unroll
    for (int t = 0; t < DEG / 2; ++t) {
        const int e = 2 * t + half;
        const int   r0 = __shfl(src0, e);
        const float a0 = __shfl(alpha0, head_a * 16 + e);
        short8 hv0 = *(const short8*)(H + (size_t)r0 * 256 + fb);
        const int   r1 = __shfl(src1, e);
        const float a1 = __shfl(alpha1, head_a * 16 + e);
        short8 hv1 = *(const short8*)(H + (size_t)r1 * 256 + fb);
#pragma unroll
        for (int k = 0; k < 8; ++k) {
            acc0[k] += a0 * bf2f((ushort)hv0[k]);
            acc1[k] += a1 * bf2f((ushort)hv1[k]);
        }
    }
#pragma unroll
    for (int k = 0; k < 8; ++k) {
        acc0[k] += __shfl_xor(acc0[k], 32);
        acc1[k] += __shfl_xor(acc1[k], 32);
    }

    const int qb = half * 4;
    *(float4*)(out + (size_t)d0 * 256 + fb + qb) =
        make_float4(acc0[qb], acc0[qb + 1], acc0[qb + 2], acc0[qb + 3]);
    *(float4*)(out + (size_t)d1 * 256 + fb + qb) =
        make_float4(acc1[qb], acc1[qb + 1], acc1[qb + 2], acc1[qb + 3]);
}

extern "C" void kernel_launch(void* const* d_in, const int* in_sizes, int n_in,
                              void* d_out, int out_size, void* d_ws, size_t ws_size,
                              hipStream_t stream) {
    const int*   col_ind = (const int*)d_in[1];
    const float* feat    = (const float*)d_in[4];
    const float* W       = (const float*)d_in[5];
    const float* attn_l  = (const float*)d_in[6];
    const float* attn_r  = (const float*)d_in[7];
    float* out = (float*)d_out;

    // ws: Wt 128KB | h_bf 25.6MB | arow 0.8MB | acol 0.8MB
    ushort* Wt   = (ushort*)d_ws;
    ushort* h_bf = Wt + 256 * 256;
    float*  arow = (float*)(h_bf + (size_t)N_NODES * HF);
    float*  acol = arow + (size_t)N_NODES * NH;

    const size_t need = (256 * 256 + (size_t)N_NODES * HF) * 2
                      + (size_t)N_NODES * NH * 4 * 2;
    if (ws_size < need) return;

    cast_wt_kernel<<<16, 256, 0, stream>>>(W, Wt);

    dim3 gg((N_NODES + 63) / 64, 2);
    mfma_gemm_kernel<<<gg, 256, 0, stream>>>(feat, Wt, attn_l, attn_r,
                                             h_bf, arow, acol, N_NODES);

    agg_kernel<<<N_NODES / 8, 256, 0, stream>>>(col_ind, h_bf, arow, acol, out);
}